// Round 1
// baseline (73.152 us; speedup 1.0000x reference)
//
#include <hip/hip_runtime.h>

#define NB 64
#define NK 49
#define NL 200
#define ND 36

__global__ __launch_bounds__(256) void alnn_fused_kernel(
    const float* __restrict__ X, const float* __restrict__ T,
    const float* __restrict__ M, const float* __restrict__ PD,
    const float* __restrict__ alpha, const float* __restrict__ w_v,
    const float4* __restrict__ w_t, const float* __restrict__ b_v,
    const float* __restrict__ b_t, float* __restrict__ out)
{
    const int bk = blockIdx.x;          // b*NK + k
    const int k  = bk % NK;
    const int b  = bk / NK;
    const int t  = threadIdx.x;

    __shared__ float part[7][ND];

    const float alpha_k = fmaxf(alpha[k], 0.0f);
    const float refk    = (float)k;     // linspace(0,48,49)[k] == k exactly

    if (t < 7 * ND) {
        const int d = t % ND;
        const int j = t / ND;

        const float*  Xp  = X   + (size_t)b * NL * ND + d;
        const float*  Tp  = T   + (size_t)b * NL * ND + d;
        const float*  Mp  = M   + (size_t)b * NL * ND + d;
        const float*  Pp  = PD  + (size_t)b * NL * ND + d;
        const float*  wvp = w_v + (size_t)k * NL * ND + d;
        const float*  btp = b_t + (size_t)k * NL * ND + d;
        const float4* wtp = w_t + (size_t)k * NL * ND + d;   // float4 units

        float acc = 0.0f;
        for (int l = j; l < NL; l += 7) {
            const int o = l * ND;
            const float x  = Xp[o];
            const float tt = Tp[o];
            const float m  = Mp[o];
            const float pd = Pp[o];
            const float4 w = wtp[o];
            const float bt = btp[o];

            const float dist  = fabsf(tt - refk);
            const float e     = __expf(-alpha_k * dist);
            const float inten = fmaxf(x * e, 0.0f);

            float s = fmaf(w.x, x,
                      fmaf(w.y, inten,
                      fmaf(w.z, m,
                      fmaf(w.w, pd, 4.0f * bt))));
            s = fmaxf(s, 0.0f);
            acc = fmaf(wvp[o], s, acc);
        }
        part[j][d] = acc;
    }
    __syncthreads();

    if (t < ND) {
        float sum = 0.0f;
        #pragma unroll
        for (int j = 0; j < 7; ++j) sum += part[j][t];
        sum += (float)NL * b_v[k * ND + t];
        out[(size_t)bk * ND + t] = fmaxf(sum, 0.0f);
    }
}

extern "C" void kernel_launch(void* const* d_in, const int* in_sizes, int n_in,
                              void* d_out, int out_size, void* d_ws, size_t ws_size,
                              hipStream_t stream) {
    const float* X     = (const float*)d_in[0];
    const float* T     = (const float*)d_in[1];
    const float* M     = (const float*)d_in[2];
    const float* PD    = (const float*)d_in[3];
    const float* alpha = (const float*)d_in[4];
    const float* w_v   = (const float*)d_in[5];
    const float* w_t   = (const float*)d_in[6];
    const float* b_v   = (const float*)d_in[7];
    const float* b_t   = (const float*)d_in[8];
    float* out = (float*)d_out;

    alnn_fused_kernel<<<NB * NK, 256, 0, stream>>>(
        X, T, M, PD, alpha, w_v, (const float4*)w_t, b_v, b_t, out);
}

// Round 2
// 38.265 us; speedup vs baseline: 1.9117x; 1.9117x over previous
//
#include <hip/hip_runtime.h>

#define NB 64
#define NK 49
#define NL 200
#define ND 36
#define LD (NL*ND)              // 7200
#define NCH 16                  // l-chunks for K2 parallelism

// workspace layout (float offsets)
#define AT_FLOATS  (LD*NB*4)                    // 1,843,200  At[ld][b][4]
#define WPK_FLOATS (LD*NK*6)                    // 2,116,800  Wpk[ld][k][6] = {wt0..3, 4*bt, wv}
#define PART_FLOATS ((size_t)ND*NCH*NK*NB)      // 1,806,336  part[d][c][k][b]
#define WPK_OFF   AT_FLOATS
#define PART_OFF  (AT_FLOATS + WPK_FLOATS)
#define WS_FULL_BYTES  ((size_t)(AT_FLOATS + WPK_FLOATS + PART_FLOATS) * 4)
#define WS_PACK_BYTES  ((size_t)(AT_FLOATS + WPK_FLOATS) * 4)

#if __has_builtin(__builtin_amdgcn_exp2f)
#define EXP2F(x) __builtin_amdgcn_exp2f(x)
#else
#define EXP2F(x) __expf((x) * 0.6931471805599453f)
#endif

// ---------------- K1: pack activations (transpose to [ld][b][4]) and weights ([ld][k][6]) ----
__global__ __launch_bounds__(256) void alnn_pack(
    const float* __restrict__ X, const float* __restrict__ T,
    const float* __restrict__ M, const float* __restrict__ PD,
    const float* __restrict__ w_v, const float4* __restrict__ w_t,
    const float* __restrict__ b_t, float* __restrict__ ws)
{
    const int bid = blockIdx.x, t = threadIdx.x;
    float4* At4 = (float4*)ws;
    float2* Wp2 = (float2*)(ws + WPK_OFF);

    if (bid < 450) {
        // activations: thread handles (b, 4 consecutive ld). 115200 threads.
        const int gid = bid * 256 + t;
        const int b = gid & 63, ld4 = gid >> 6;          // ld4 in [0,1800)
        const float4* X4 = (const float4*)X;
        const float4* T4 = (const float4*)T;
        const float4* M4 = (const float4*)M;
        const float4* P4 = (const float4*)PD;
        const int src = b * (LD / 4) + ld4;              // b*1800 + ld4
        const float4 x4 = X4[src], t4 = T4[src], m4 = M4[src], p4 = P4[src];
        const int ldb = ld4 * 4;
        At4[(ldb + 0) * 64 + b] = make_float4(x4.x, t4.x, m4.x, p4.x);
        At4[(ldb + 1) * 64 + b] = make_float4(x4.y, t4.y, m4.y, p4.y);
        At4[(ldb + 2) * 64 + b] = make_float4(x4.z, t4.z, m4.z, p4.z);
        At4[(ldb + 3) * 64 + b] = make_float4(x4.w, t4.w, m4.w, p4.w);
    } else {
        // weights: thread handles one (ld, k). 352800 threads (ragged guard).
        const int j = (bid - 450) * 256 + t;
        if (j < LD * NK) {
            const int ld = j / NK, k = j - ld * NK;
            const float4 wt = w_t[k * LD + ld];
            const float  bt = b_t[k * LD + ld];
            const float  wv = w_v[k * LD + ld];
            Wp2[j * 3 + 0] = make_float2(wt.x, wt.y);
            Wp2[j * 3 + 1] = make_float2(wt.z, wt.w);
            Wp2[j * 3 + 2] = make_float2(4.0f * bt, wv);
        }
    }
}

// ---------------- K2: main fused compute. block = (d, l-chunk); lane = b; wave owns k-subset --
template<int ATOMIC>
__global__ __launch_bounds__(512) void alnn_main(
    const float* __restrict__ ws_ro, const float* __restrict__ alpha,
    float* __restrict__ dst)   // part[] (ws path) or out[] (atomic path)
{
    __shared__ float lw[13 * NK * 8];                    // 20384 B

    const int bid = blockIdx.x, t = threadIdx.x;
    const int d = bid % ND, c = bid / ND;
    const int len = (c < 8) ? 13 : 12;
    const int l0  = (c < 8) ? 13 * c : 104 + 12 * (c - 8);
    const int wave = t >> 6, b = t & 63;
    const int k0 = 6 * wave;
    const int nk = (wave == 7) ? 7 : 6;

    const float4* At4 = (const float4*)ws_ro;
    const float*  Wpk = ws_ro + WPK_OFF;

    // stage this (d, l-chunk)'s weights into LDS as [row][k][8]
    const int pairs = len * NK;
    for (int j = t; j < pairs; j += 512) {
        const int row = j / NK, k = j - row * NK;
        const float2* s2 = (const float2*)(Wpk + (((l0 + row) * ND + d) * NK + k) * 6);
        float* w = lw + (row * NK + k) * 8;
        ((float2*)w)[0] = s2[0];
        ((float2*)w)[1] = s2[1];
        ((float2*)w)[2] = s2[2];
    }

    float ar[7], rk[7];
    #pragma unroll
    for (int kk = 0; kk < 7; kk++) {
        const int k = k0 + kk;
        const float a = (kk < nk) ? alpha[k] : 0.0f;
        ar[kk] = fmaxf(a, 0.0f) * 1.44269504088896f;     // fold log2(e) for exp2
        rk[kk] = (float)k;                               // linspace(0,48,49)[k] == k
    }
    __syncthreads();

    float acc[7] = {0, 0, 0, 0, 0, 0, 0};

#define K_BODY(kk)                                                        \
    {                                                                     \
        const float4 wt = *(const float4*)(lw + base + (kk) * 8);         \
        const float2 cw = *(const float2*)(lw + base + (kk) * 8 + 4);     \
        const float dist  = fabsf(av.y - rk[kk]);                         \
        const float e     = EXP2F(-ar[kk] * dist);                        \
        const float inten = fmaxf(av.x * e, 0.0f);                        \
        float s = wt.x * av.x + wt.y * inten + wt.z * av.z + wt.w * av.w  \
                  + cw.x;                                                 \
        s = fmaxf(s, 0.0f);                                               \
        acc[kk] += cw.y * s;                                              \
    }

    for (int ll = 0; ll < len; ll++) {
        const float4 av = At4[((l0 + ll) * ND + d) * 64 + b];
        const int base = (ll * NK + k0) * 8;
        K_BODY(0) K_BODY(1) K_BODY(2) K_BODY(3) K_BODY(4) K_BODY(5)
        if (nk == 7) K_BODY(6)
    }
#undef K_BODY

    if (ATOMIC) {
        #pragma unroll
        for (int kk = 0; kk < 7; kk++)
            if (kk < nk)
                atomicAdd(&dst[(b * NK + (k0 + kk)) * ND + d], acc[kk]);
    } else {
        #pragma unroll
        for (int kk = 0; kk < 7; kk++)
            if (kk < nk)
                dst[(((size_t)d * NCH + c) * NK + (k0 + kk)) * 64 + b] = acc[kk];
    }
}

// ---------------- K3: reduce l-chunk partials + bias + relu --------------------------------
__global__ __launch_bounds__(256) void alnn_reduce(
    const float* __restrict__ part, const float* __restrict__ b_v,
    float* __restrict__ out)
{
    const int bid = blockIdx.x, t = threadIdx.x;
    const int d = bid >> 2, q = bid & 3;                 // 144 blocks = 36 d x 4 b-quarters
    for (int j = t; j < NK * 16; j += 256) {
        const int k = j >> 4, b = q * 16 + (j & 15);
        float sum = 0.0f;
        #pragma unroll
        for (int c = 0; c < NCH; c++)
            sum += part[(((size_t)d * NCH + c) * NK + k) * 64 + b];
        out[(b * NK + k) * ND + d] = fmaxf(sum + 200.0f * b_v[k * ND + d], 0.0f);
    }
}

// ---------------- K3b: atomic-path epilogue (in-place bias + relu) -------------------------
__global__ __launch_bounds__(256) void alnn_finish(
    const float* __restrict__ b_v, float* __restrict__ out)
{
    const int i = blockIdx.x * 256 + threadIdx.x;
    if (i < NB * NK * ND) {
        const int r = i % (NK * ND);                     // = k*ND + d
        out[i] = fmaxf(out[i] + 200.0f * b_v[r], 0.0f);
    }
}

// ---------------- legacy fallback (proven round-1 kernel) ----------------------------------
__global__ __launch_bounds__(256) void alnn_fused_kernel(
    const float* __restrict__ X, const float* __restrict__ T,
    const float* __restrict__ M, const float* __restrict__ PD,
    const float* __restrict__ alpha, const float* __restrict__ w_v,
    const float4* __restrict__ w_t, const float* __restrict__ b_v,
    const float* __restrict__ b_t, float* __restrict__ out)
{
    const int bk = blockIdx.x;
    const int k  = bk % NK;
    const int b  = bk / NK;
    const int t  = threadIdx.x;

    __shared__ float part[7][ND];

    const float alpha_k = fmaxf(alpha[k], 0.0f);
    const float refk    = (float)k;

    if (t < 7 * ND) {
        const int d = t % ND;
        const int j = t / ND;
        const float*  Xp  = X   + (size_t)b * LD + d;
        const float*  Tp  = T   + (size_t)b * LD + d;
        const float*  Mp  = M   + (size_t)b * LD + d;
        const float*  Pp  = PD  + (size_t)b * LD + d;
        const float*  wvp = w_v + (size_t)k * LD + d;
        const float*  btp = b_t + (size_t)k * LD + d;
        const float4* wtp = w_t + (size_t)k * LD + d;

        float acc = 0.0f;
        for (int l = j; l < NL; l += 7) {
            const int o = l * ND;
            const float x  = Xp[o];
            const float tt = Tp[o];
            const float m  = Mp[o];
            const float pd = Pp[o];
            const float4 w = wtp[o];
            const float bt = btp[o];
            const float dist  = fabsf(tt - refk);
            const float e     = __expf(-alpha_k * dist);
            const float inten = fmaxf(x * e, 0.0f);
            float s = fmaf(w.x, x, fmaf(w.y, inten, fmaf(w.z, m, fmaf(w.w, pd, 4.0f * bt))));
            s = fmaxf(s, 0.0f);
            acc = fmaf(wvp[o], s, acc);
        }
        part[j][d] = acc;
    }
    __syncthreads();

    if (t < ND) {
        float sum = 0.0f;
        #pragma unroll
        for (int j = 0; j < 7; ++j) sum += part[j][t];
        sum += (float)NL * b_v[k * ND + t];
        out[(size_t)bk * ND + t] = fmaxf(sum, 0.0f);
    }
}

extern "C" void kernel_launch(void* const* d_in, const int* in_sizes, int n_in,
                              void* d_out, int out_size, void* d_ws, size_t ws_size,
                              hipStream_t stream) {
    const float* X     = (const float*)d_in[0];
    const float* T     = (const float*)d_in[1];
    const float* M     = (const float*)d_in[2];
    const float* PD    = (const float*)d_in[3];
    const float* alpha = (const float*)d_in[4];
    const float* w_v   = (const float*)d_in[5];
    const float* w_t   = (const float*)d_in[6];
    const float* b_v   = (const float*)d_in[7];
    const float* b_t   = (const float*)d_in[8];
    float* out = (float*)d_out;
    float* ws  = (float*)d_ws;

    const int pack_grid = 450 + (LD * NK + 255) / 256;   // 450 + 1379 = 1829

    if (ws_size >= WS_FULL_BYTES) {
        alnn_pack<<<pack_grid, 256, 0, stream>>>(X, T, M, PD, w_v, (const float4*)w_t, b_t, ws);
        alnn_main<0><<<ND * NCH, 512, 0, stream>>>(ws, alpha, ws + PART_OFF);
        alnn_reduce<<<ND * 4, 256, 0, stream>>>(ws + PART_OFF, b_v, out);
    } else if (ws_size >= WS_PACK_BYTES) {
        hipMemsetAsync(out, 0, (size_t)out_size * sizeof(float), stream);
        alnn_pack<<<pack_grid, 256, 0, stream>>>(X, T, M, PD, w_v, (const float4*)w_t, b_t, ws);
        alnn_main<1><<<ND * NCH, 512, 0, stream>>>(ws, alpha, out);
        alnn_finish<<<(NB * NK * ND + 255) / 256, 256, 0, stream>>>(b_v, out);
    } else {
        alnn_fused_kernel<<<NB * NK, 256, 0, stream>>>(
            X, T, M, PD, alpha, w_v, (const float4*)w_t, b_v, b_t, out);
    }
}

// Round 3
// 36.825 us; speedup vs baseline: 1.9865x; 1.0391x over previous
//
#include <hip/hip_runtime.h>

#define NB 64
#define NK 49
#define NL 200
#define ND 36
#define LD (NL*ND)              // 7200
#define NCH 16                  // l-chunks for K2 parallelism

// workspace layout (float offsets)
#define AT_FLOATS  (LD*NB*4)                    // At[ld][b][4] = {x,t,m,pd}
#define WPK_FLOATS (LD*NK*6)                    // Wpk[ld][k][6] = {wt0..3, 4*bt, wv}
#define PART_FLOATS ((size_t)ND*NCH*NK*NB)      // part[d][c][k][b]
#define WPK_OFF   AT_FLOATS
#define PART_OFF  (AT_FLOATS + WPK_FLOATS)
#define WS_FULL_BYTES ((size_t)(AT_FLOATS + WPK_FLOATS + PART_FLOATS) * 4)

#define LOG2E 1.44269504088896f

#if __has_builtin(__builtin_amdgcn_exp2f)
#define EXP2F(x) __builtin_amdgcn_exp2f(x)
#else
#define EXP2F(x) __expf((x) * 0.6931471805599453f)
#endif

// ---------------- K1: LDS-transposed packs (coalesced on both sides) ----------------------
__global__ __launch_bounds__(256) void alnn_pack(
    const float* __restrict__ X, const float* __restrict__ T,
    const float* __restrict__ M, const float* __restrict__ PD,
    const float* __restrict__ w_v, const float4* __restrict__ w_t,
    const float* __restrict__ b_t, float* __restrict__ ws)
{
    __shared__ float tile[9440];
    const int bid = blockIdx.x, t = threadIdx.x;

    if (bid < 225) {
        // activations: tile covers 32 ld x 64 b for {X,T,M,PD}; layout [a][b][33]
        const int ld0 = bid * 32;
        const int ld = t & 31, bq = t >> 5;
        const float* src[4] = {X, T, M, PD};
        #pragma unroll
        for (int a = 0; a < 4; a++) {
            const float* A = src[a];
            for (int b = bq; b < 64; b += 8)
                tile[(a * 64 + b) * 33 + ld] = A[b * LD + ld0 + ld];
        }
        __syncthreads();
        float4* At4 = (float4*)ws;
        const int b = t & 63, ldq = t >> 6;
        #pragma unroll
        for (int r = 0; r < 8; r++) {
            const int l = ldq * 8 + r;
            float4 v;
            v.x = tile[(0 * 64 + b) * 33 + l];
            v.y = tile[(1 * 64 + b) * 33 + l];
            v.z = tile[(2 * 64 + b) * 33 + l];
            v.w = tile[(3 * 64 + b) * 33 + l];
            At4[(size_t)(ld0 + l) * 64 + b] = v;
        }
    } else {
        // weights: tile covers 32 ld x 49 k x 6; layout [ld][295] (odd stride, conflict-free)
        const int ld0 = (bid - 225) * 32;
        const int ld = t & 31, kq = t >> 5;
        for (int k = kq; k < NK; k += 8) {
            const float4 wt = w_t[(size_t)k * LD + ld0 + ld];
            const float  bt = b_t[(size_t)k * LD + ld0 + ld];
            const float  wv = w_v[(size_t)k * LD + ld0 + ld];
            float* w = tile + ld * 295 + k * 6;
            w[0] = wt.x; w[1] = wt.y; w[2] = wt.z; w[3] = wt.w;
            w[4] = 4.0f * bt; w[5] = wv;
        }
        __syncthreads();
        float* Wpk = ws + WPK_OFF + (size_t)ld0 * (NK * 6);
        for (int i = t; i < 32 * NK * 6; i += 256) {
            const int l = i / (NK * 6), r = i - l * (NK * 6);
            Wpk[i] = tile[l * 295 + r];
        }
    }
}

// ---------------- K2: fused compute, scalar (wave-uniform) weight loads, no LDS -----------
__global__ __launch_bounds__(512) void alnn_main(
    const float* __restrict__ ws_ro, const float* __restrict__ alpha,
    float* __restrict__ part)
{
    const int bid = blockIdx.x, t = threadIdx.x;
    const int d = bid % ND, c = bid / ND;
    const int len = (c < 8) ? 13 : 12;
    const int l0  = (c < 8) ? 13 * c : 104 + 12 * (c - 8);
    const int b = t & 63;
    const int k0 = __builtin_amdgcn_readfirstlane((t >> 6) * 6);  // wave-uniform
    const int nk = (k0 == 42) ? 7 : 6;

    const float4* At4 = (const float4*)ws_ro;
    const float*  Wpk = ws_ro + WPK_OFF;

    float arn[7], rk[7];
    #pragma unroll
    for (int kk = 0; kk < 7; kk++) {                 // k0+6 <= 48, always in range
        arn[kk] = -fmaxf(alpha[k0 + kk], 0.0f) * LOG2E;
        rk[kk]  = (float)(k0 + kk);
    }

    float acc[7] = {0, 0, 0, 0, 0, 0, 0};

#define K_BODY(kk) {                                                       \
        const float* w = wrow + (kk) * 6;                                  \
        const float dist = fabsf(av.y - rk[kk]);                           \
        const float e    = EXP2F(arn[kk] * dist);                          \
        float s = w[0] * av.x + w[1] * (xp * e) + w[2] * av.z              \
                + w[3] * av.w + w[4];                                      \
        acc[kk] += w[5] * fmaxf(s, 0.0f); }

    for (int ll = 0; ll < len; ll++) {
        const int ld = (l0 + ll) * ND + d;
        const float4 av = At4[(size_t)ld * 64 + b];
        const float xp = fmaxf(av.x, 0.0f);          // relu(x*e) == relu(x)*e, e>0
        const float* wrow = Wpk + ((size_t)ld * NK + k0) * 6;
        K_BODY(0) K_BODY(1) K_BODY(2) K_BODY(3) K_BODY(4) K_BODY(5)
        if (nk == 7) K_BODY(6)
    }
#undef K_BODY

    #pragma unroll
    for (int kk = 0; kk < 7; kk++)
        if (kk < nk)
            part[(((size_t)d * NCH + c) * NK + (k0 + kk)) * 64 + b] = acc[kk];
}

// ---------------- K3: reduce l-chunk partials + bias + relu -------------------------------
__global__ __launch_bounds__(256) void alnn_reduce(
    const float* __restrict__ part, const float* __restrict__ b_v,
    float* __restrict__ out)
{
    const int bid = blockIdx.x, t = threadIdx.x;
    const int d = bid >> 3, oct = bid & 7;           // 288 blocks = 36 d x 8 b-octets
    for (int j = t; j < NK * 8; j += 256) {
        const int k = j >> 3, b = oct * 8 + (j & 7);
        float sum = 0.0f;
        #pragma unroll
        for (int cc = 0; cc < NCH; cc++)
            sum += part[(((size_t)d * NCH + cc) * NK + k) * 64 + b];
        out[(b * NK + k) * ND + d] = fmaxf(sum + 200.0f * b_v[k * ND + d], 0.0f);
    }
}

// ---------------- legacy fallback (proven round-1 kernel) ----------------------------------
__global__ __launch_bounds__(256) void alnn_fused_kernel(
    const float* __restrict__ X, const float* __restrict__ T,
    const float* __restrict__ M, const float* __restrict__ PD,
    const float* __restrict__ alpha, const float* __restrict__ w_v,
    const float4* __restrict__ w_t, const float* __restrict__ b_v,
    const float* __restrict__ b_t, float* __restrict__ out)
{
    const int bk = blockIdx.x;
    const int k  = bk % NK;
    const int b  = bk / NK;
    const int t  = threadIdx.x;

    __shared__ float part[7][ND];

    const float alpha_k = fmaxf(alpha[k], 0.0f);
    const float refk    = (float)k;

    if (t < 7 * ND) {
        const int d = t % ND;
        const int j = t / ND;
        const float*  Xp  = X   + (size_t)b * LD + d;
        const float*  Tp  = T   + (size_t)b * LD + d;
        const float*  Mp  = M   + (size_t)b * LD + d;
        const float*  Pp  = PD  + (size_t)b * LD + d;
        const float*  wvp = w_v + (size_t)k * LD + d;
        const float*  btp = b_t + (size_t)k * LD + d;
        const float4* wtp = w_t + (size_t)k * LD + d;

        float acc = 0.0f;
        for (int l = j; l < NL; l += 7) {
            const int o = l * ND;
            const float x  = Xp[o];
            const float tt = Tp[o];
            const float m  = Mp[o];
            const float pd = Pp[o];
            const float4 w = wtp[o];
            const float bt = btp[o];
            const float dist  = fabsf(tt - refk);
            const float e     = __expf(-alpha_k * dist);
            const float inten = fmaxf(x * e, 0.0f);
            float s = fmaf(w.x, x, fmaf(w.y, inten, fmaf(w.z, m, fmaf(w.w, pd, 4.0f * bt))));
            s = fmaxf(s, 0.0f);
            acc = fmaf(wvp[o], s, acc);
        }
        part[j][d] = acc;
    }
    __syncthreads();

    if (t < ND) {
        float sum = 0.0f;
        #pragma unroll
        for (int j = 0; j < 7; ++j) sum += part[j][t];
        sum += (float)NL * b_v[k * ND + t];
        out[(size_t)bk * ND + t] = fmaxf(sum, 0.0f);
    }
}

extern "C" void kernel_launch(void* const* d_in, const int* in_sizes, int n_in,
                              void* d_out, int out_size, void* d_ws, size_t ws_size,
                              hipStream_t stream) {
    const float* X     = (const float*)d_in[0];
    const float* T     = (const float*)d_in[1];
    const float* M     = (const float*)d_in[2];
    const float* PD    = (const float*)d_in[3];
    const float* alpha = (const float*)d_in[4];
    const float* w_v   = (const float*)d_in[5];
    const float* w_t   = (const float*)d_in[6];
    const float* b_v   = (const float*)d_in[7];
    const float* b_t   = (const float*)d_in[8];
    float* out = (float*)d_out;
    float* ws  = (float*)d_ws;

    if (ws_size >= WS_FULL_BYTES) {
        alnn_pack<<<450, 256, 0, stream>>>(X, T, M, PD, w_v, (const float4*)w_t, b_t, ws);
        alnn_main<<<ND * NCH, 512, 0, stream>>>(ws, alpha, ws + PART_OFF);
        alnn_reduce<<<288, 256, 0, stream>>>(ws + PART_OFF, b_v, out);
    } else {
        alnn_fused_kernel<<<NB * NK, 256, 0, stream>>>(
            X, T, M, PD, alpha, w_v, (const float4*)w_t, b_v, b_t, out);
    }
}